// Round 1
// baseline (338.261 us; speedup 1.0000x reference)
//
#include <hip/hip_runtime.h>
#include <math.h>

// n=16384 points in 3D. Exact 12-NN (incl. self) per point via brute force,
// then closed-form GCNConv + mean:
//   out[i] = b + ( (W·p_i)·(1 + 11/sqrt(2)) + 0.5 * sum_{j in 11NN} W·|p_i - p_j| ) / 12
//
// Design: 8 slice-threads per query, block=256 -> 32 queries/block, grid=512.
// Phase 1: distance-only top-12 per slice via branch-free med3 sorted insert.
// Merge (8-way) -> tau = 12th smallest distance (self d2=0 is one of them).
// Phase 2: rescan, accumulate W·|diff| for d2 <= tau (self contributes 0).

#define BLOCK  256
#define NSLICE 8
#define QPB    (BLOCK / NSLICE)   // 32 queries per block
#define TILE   1024
#define KK     12

__global__ __launch_bounds__(BLOCK)
void knn_gcn_kernel(const float* __restrict__ p,
                    const float* __restrict__ W,
                    const float* __restrict__ bias,
                    float* __restrict__ out, int n) {
  __shared__ __align__(16) float s_c[3 * TILE];   // SoA: [c*TILE + j]
  __shared__ float s_d[BLOCK * KK];               // per-thread sorted top-12
  __shared__ float s_tau[QPB];
  __shared__ float s_part[BLOCK];

  const int tid = threadIdx.x;
  const int sl  = tid & (NSLICE - 1);
  const int ql  = tid >> 3;
  const int i   = blockIdx.x * QPB + ql;
  const int iq  = (i < n) ? i : 0;

  const float xi = p[3 * iq + 0];
  const float yi = p[3 * iq + 1];
  const float zi = p[3 * iq + 2];

  float dist[KK];
#pragma unroll
  for (int t = 0; t < KK; ++t) dist[t] = 3.0e38f;

  const int n3 = 3 * n;

  // ---------------- phase 1: per-slice top-12 distances ----------------
  for (int base = 0; base < n; base += TILE) {
    __syncthreads();
#pragma unroll
    for (int u0 = 0; u0 < 3 * TILE; u0 += BLOCK) {
      const int u = u0 + tid;
      const int g = base * 3 + u;
      const float v = (g < n3) ? p[g] : 1.0e30f;  // pad -> huge d2, never selected
      const int cand = u / 3;
      const int c = u - cand * 3;
      s_c[c * TILE + cand] = v;
    }
    __syncthreads();

#pragma unroll 2
    for (int g = sl; g < TILE / 4; g += NSLICE) {
      const int cb = g * 4;
      const float4 X = *(const float4*)&s_c[cb];
      const float4 Y = *(const float4*)&s_c[TILE + cb];
      const float4 Z = *(const float4*)&s_c[2 * TILE + cb];

      float d2v[4];
      {
        const float dx = xi - X.x, dy = yi - Y.x, dz = zi - Z.x;
        d2v[0] = dx * dx + dy * dy + dz * dz;
      }
      {
        const float dx = xi - X.y, dy = yi - Y.y, dz = zi - Z.y;
        d2v[1] = dx * dx + dy * dy + dz * dz;
      }
      {
        const float dx = xi - X.z, dy = yi - Y.z, dz = zi - Z.z;
        d2v[2] = dx * dx + dy * dy + dz * dz;
      }
      {
        const float dx = xi - X.w, dy = yi - Y.w, dz = zi - Z.w;
        d2v[3] = dx * dx + dy * dy + dz * dz;
      }

      // branch-free sorted insert: 11 med3 + 1 min per candidate
#pragma unroll
      for (int e = 0; e < 4; ++e) {
        const float d = d2v[e];
#pragma unroll
        for (int t = KK - 1; t >= 1; --t)
          dist[t] = __builtin_amdgcn_fmed3f(d, dist[t - 1], dist[t]);
        dist[0] = fminf(dist[0], d);
      }
    }
  }

  // ---------------- merge 8 sorted lists -> tau (12th smallest) --------
  __syncthreads();
#pragma unroll
  for (int t = 0; t < KK; ++t) s_d[tid * KK + t] = dist[t];
  __syncthreads();

  if (sl == 0) {
    int h[NSLICE];
#pragma unroll
    for (int t = 0; t < NSLICE; ++t) h[t] = 0;
    float tau = 0.0f;
    for (int r = 0; r < KK; ++r) {
      float best = 3.4e38f;
      int bs = 0;
#pragma unroll
      for (int t = 0; t < NSLICE; ++t) {
        const float v = s_d[(tid + t) * KK + h[t]];
        if (v < best) { best = v; bs = t; }
      }
#pragma unroll
      for (int t = 0; t < NSLICE; ++t) h[t] += (bs == t) ? 1 : 0;
      tau = best;
    }
    s_tau[ql] = tau;
  }
  __syncthreads();

  const float tau = s_tau[ql];
  const float W0 = W[0], W1 = W[1], W2 = W[2];

  // ---------------- phase 2: accumulate W·|diff| for d2 <= tau ---------
  float acc = 0.0f;
  for (int base = 0; base < n; base += TILE) {
    __syncthreads();
#pragma unroll
    for (int u0 = 0; u0 < 3 * TILE; u0 += BLOCK) {
      const int u = u0 + tid;
      const int g = base * 3 + u;
      const float v = (g < n3) ? p[g] : 1.0e30f;
      const int cand = u / 3;
      const int c = u - cand * 3;
      s_c[c * TILE + cand] = v;
    }
    __syncthreads();

#pragma unroll 2
    for (int g = sl; g < TILE / 4; g += NSLICE) {
      const int cb = g * 4;
      const float4 X = *(const float4*)&s_c[cb];
      const float4 Y = *(const float4*)&s_c[TILE + cb];
      const float4 Z = *(const float4*)&s_c[2 * TILE + cb];

      const float dx0 = xi - X.x, dy0 = yi - Y.x, dz0 = zi - Z.x;
      const float dx1 = xi - X.y, dy1 = yi - Y.y, dz1 = zi - Z.y;
      const float dx2 = xi - X.z, dy2 = yi - Y.z, dz2 = zi - Z.z;
      const float dx3 = xi - X.w, dy3 = yi - Y.w, dz3 = zi - Z.w;
      const float d20 = dx0 * dx0 + dy0 * dy0 + dz0 * dz0;
      const float d21 = dx1 * dx1 + dy1 * dy1 + dz1 * dz1;
      const float d22 = dx2 * dx2 + dy2 * dy2 + dz2 * dz2;
      const float d23 = dx3 * dx3 + dy3 * dy3 + dz3 * dz3;

      const bool h0 = (d20 <= tau), h1 = (d21 <= tau);
      const bool h2 = (d22 <= tau), h3 = (d23 <= tau);
      if (h0 | h1 | h2 | h3) {
        if (h0) acc += W0 * fabsf(dx0) + W1 * fabsf(dy0) + W2 * fabsf(dz0);
        if (h1) acc += W0 * fabsf(dx1) + W1 * fabsf(dy1) + W2 * fabsf(dz1);
        if (h2) acc += W0 * fabsf(dx2) + W1 * fabsf(dy2) + W2 * fabsf(dz2);
        if (h3) acc += W0 * fabsf(dx3) + W1 * fabsf(dy3) + W2 * fabsf(dz3);
      }
    }
  }

  s_part[tid] = acc;
  __syncthreads();

  if (sl == 0 && i < n) {
    float sum = 0.0f;
#pragma unroll
    for (int t = 0; t < NSLICE; ++t) sum += s_part[tid + t];
    const float xw0 = W0 * xi + W1 * yi + W2 * zi;
    // 1 + 11/sqrt(2) = 8.778174593052022...
    out[i] = bias[0] + (xw0 * 8.778174593052022f + 0.5f * sum) * (1.0f / 12.0f);
  }
}

extern "C" void kernel_launch(void* const* d_in, const int* in_sizes, int n_in,
                              void* d_out, int out_size, void* d_ws, size_t ws_size,
                              hipStream_t stream) {
  const float* p  = (const float*)d_in[0];
  const float* W  = (const float*)d_in[1];
  const float* bb = (const float*)d_in[2];
  float* out = (float*)d_out;

  const int n = in_sizes[0] / 3;              // 16384
  const int grid = (n + QPB - 1) / QPB;       // 512 blocks

  knn_gcn_kernel<<<grid, BLOCK, 0, stream>>>(p, W, bb, out, n);
}